// Round 2
// baseline (99.275 us; speedup 1.0000x reference)
//
#include <hip/hip_runtime.h>
#include <math.h>

#define DIN 512
#define NQ 4
#define DEPTH 6

typedef float fx4 __attribute__((ext_vector_type(4)));

__device__ __forceinline__ float shflx(float v, int mask) {
    return __shfl_xor(v, mask, 64);
}

__device__ __forceinline__ float rfl(float x) {
    return __uint_as_float(__builtin_amdgcn_readfirstlane(__float_as_uint(x)));
}

__global__ __launch_bounds__(256, 4) void qnet_kernel(
    const float* __restrict__ x,       // (B, 512)
    const float* __restrict__ pre_w,   // (4, 512)
    const float* __restrict__ pre_b,   // (4,)
    const float* __restrict__ qp,      // (24,)
    const float* __restrict__ post_w,  // (2, 4)
    const float* __restrict__ post_b,  // (2,)
    float* __restrict__ out,           // (B, 2)
    int B)
{
    __shared__ float qbuf[4][64][5];   // [wave][row-in-batch][qubit], +1 pad

    const int tid  = threadIdx.x;
    const int lane = tid & 63;
    const int wv   = tid >> 6;
    const long long wave_global = ((long long)blockIdx.x * (long long)blockDim.x + tid) >> 6;
    const long long row_base = wave_global * 64;

    const int c0 = lane * 4;          // cols [0,256) as lane*4
    const int c1 = 256 + lane * 4;    // cols [256,512)

    // pre_w fragment: 8 floats per qubit per lane, loaded once (L1/L2-hot, tiny)
    fx4 w0[NQ], w1[NQ];
#pragma unroll
    for (int q = 0; q < NQ; ++q) {
        w0[q] = *reinterpret_cast<const fx4*>(pre_w + q * DIN + c0);
        w1[q] = *reinterpret_cast<const fx4*>(pre_w + q * DIN + c1);
    }

    const bool odd  = (lane & 1) != 0;
    const bool bit2 = (lane & 2) != 0;
    const int  quad = lane >> 2;
    const int  qq   = lane & 3;

    const long long maxrow = (long long)B - 1;

    // ---- Phase 1: 64 rows per wave; coalesced row loads + merged butterfly ----
#pragma unroll 4
    for (int j = 0; j < 64; ++j) {
        long long row = row_base + j;
        if (row > maxrow) row = maxrow;          // clamp (B is a multiple of 64 in practice)
        const float* xr = x + row * DIN;
        fx4 a = __builtin_nontemporal_load(reinterpret_cast<const fx4*>(xr + c0));
        fx4 b = __builtin_nontemporal_load(reinterpret_cast<const fx4*>(xr + c1));

        float p[NQ];
#pragma unroll
        for (int q = 0; q < NQ; ++q) {
            float s = a.x * w0[q].x;
            s = fmaf(a.y, w0[q].y, s);
            s = fmaf(a.z, w0[q].z, s);
            s = fmaf(a.w, w0[q].w, s);
            s = fmaf(b.x, w1[q].x, s);
            s = fmaf(b.y, w1[q].y, s);
            s = fmaf(b.z, w1[q].z, s);
            s = fmaf(b.w, w1[q].w, s);
            p[q] = s;
        }

        // merged reduction: fold the 4 q-values into lane%4 slots during xor-1/xor-2
        float s0 = p[0] + shflx(p[0], 1);
        float s1 = p[1] + shflx(p[1], 1);
        float s2 = p[2] + shflx(p[2], 1);
        float s3 = p[3] + shflx(p[3], 1);
        float a01 = odd  ? s1 : s0;
        float a23 = odd  ? s3 : s2;
        float u01 = a01 + shflx(a01, 2);
        float u23 = a23 + shflx(a23, 2);
        float c = bit2 ? u23 : u01;     // lane l now holds quad-partial of dot[l&3]
        c += shflx(c, 4);
        c += shflx(c, 8);
        c += shflx(c, 16);
        c += shflx(c, 32);              // full sum of dot[l&3] on every lane

        if (quad == (j & 15)) qbuf[wv][j][qq] = c;   // 4 lanes deposit row j's 4 dots
    }

    __syncthreads();   // wave-local dependency really, but cheap & safe

    // ---- Phase 2: each lane simulates the circuit for its own row ----
    float d0 = qbuf[wv][lane][0] + pre_b[0];
    float d1 = qbuf[wv][lane][1] + pre_b[1];
    float d2 = qbuf[wv][lane][2] + pre_b[2];
    float d3 = qbuf[wv][lane][3] + pre_b[3];

    const float QPI = 0.7853981633974483f;   // pi/4: half of q_in = tanh*pi/2
    float h0 = QPI * tanhf(d0);
    float h1 = QPI * tanhf(d1);
    float h2 = QPI * tanhf(d2);
    float h3 = QPI * tanhf(d3);

    float cc[NQ], ss[NQ];
    __sincosf(h0, &ss[0], &cc[0]);
    __sincosf(h1, &ss[1], &cc[1]);
    __sincosf(h2, &ss[2], &cc[2]);
    __sincosf(h3, &ss[3], &cc[3]);

    // per-wire 2-vector after H then RY(theta_w): ((c-s)/sqrt2, (c+s)/sqrt2)
    const float RS2 = 0.7071067811865476f;
    float e[NQ][2];
#pragma unroll
    for (int w = 0; w < NQ; ++w) {
        e[w][0] = (cc[w] - ss[w]) * RS2;
        e[w][1] = (cc[w] + ss[w]) * RS2;
    }

    // idx = i0*8 + i1*4 + i2*2 + i3   (wire w <-> bit 3-w)
    float st[16];
#pragma unroll
    for (int hi = 0; hi < 4; ++hi) {
        float m01 = e[0][hi >> 1] * e[1][hi & 1];
#pragma unroll
        for (int lo = 0; lo < 4; ++lo) {
            st[hi * 4 + lo] = m01 * (e[2][lo >> 1] * e[3][lo & 1]);
        }
    }

#pragma unroll
    for (int k = 0; k < DEPTH; ++k) {
        // CNOT(0,1): idx bit3=1 -> flip bit2 : swap 8..11 <-> 12..15
#pragma unroll
        for (int m = 0; m < 4; ++m) { float t = st[8 + m]; st[8 + m] = st[12 + m]; st[12 + m] = t; }
        // CNOT(2,3): idx bit1=1 -> flip bit0 : swap (2,3),(6,7),(10,11),(14,15)
#pragma unroll
        for (int m = 0; m < 4; ++m) { int i = 4 * m + 2; float t = st[i]; st[i] = st[i + 1]; st[i + 1] = t; }
        // CNOT(1,2): idx bit2=1 -> flip bit1 : swap (4,6),(5,7),(12,14),(13,15)
        {
            float t;
            t = st[4];  st[4]  = st[6];  st[6]  = t;
            t = st[5];  st[5]  = st[7];  st[7]  = t;
            t = st[12]; st[12] = st[14]; st[14] = t;
            t = st[13]; st[13] = st[15]; st[15] = t;
        }
        // RY(qw[k][w]) on each wire; angles wave-uniform -> SGPR via readfirstlane
#pragma unroll
        for (int w = 0; w < NQ; ++w) {
            float ang = 0.5f * qp[k * NQ + w];
            float sk, ck;
            __sincosf(ang, &sk, &ck);
            ck = rfl(ck);
            sk = rfl(sk);
            const int mask = 8 >> w;
#pragma unroll
            for (int i = 0; i < 16; ++i) {
                if ((i & mask) == 0) {
                    float lo = st[i], hi = st[i + mask];
                    st[i]        = fmaf(ck, lo, -(sk * hi));
                    st[i + mask] = fmaf(sk, lo, ck * hi);
                }
            }
        }
    }

    // Z expectations: z_w = sum_i sign(bit(3-w) of i) * st[i]^2
    float z0 = 0.f, z1 = 0.f, z2 = 0.f, z3 = 0.f;
#pragma unroll
    for (int i = 0; i < 16; ++i) {
        float pr = st[i] * st[i];
        z0 += (i & 8) ? -pr : pr;
        z1 += (i & 4) ? -pr : pr;
        z2 += (i & 2) ? -pr : pr;
        z3 += (i & 1) ? -pr : pr;
    }

    float o0 = fmaf(z0, post_w[0], fmaf(z1, post_w[1], fmaf(z2, post_w[2], fmaf(z3, post_w[3], post_b[0]))));
    float o1 = fmaf(z0, post_w[4], fmaf(z1, post_w[5], fmaf(z2, post_w[6], fmaf(z3, post_w[7], post_b[1]))));

    long long row = row_base + lane;
    if (row < (long long)B) {
        float2 o; o.x = o0; o.y = o1;
        *reinterpret_cast<float2*>(out + row * 2) = o;
    }
}

extern "C" void kernel_launch(void* const* d_in, const int* in_sizes, int n_in,
                              void* d_out, int out_size, void* d_ws, size_t ws_size,
                              hipStream_t stream) {
    const float* x      = (const float*)d_in[0];
    const float* pre_w  = (const float*)d_in[1];
    const float* pre_b  = (const float*)d_in[2];
    const float* qp     = (const float*)d_in[3];
    const float* post_w = (const float*)d_in[4];
    const float* post_b = (const float*)d_in[5];
    float* out = (float*)d_out;

    const int B = in_sizes[0] / DIN;
    if (B <= 0) return;
    const int blocks = (B + 255) / 256;   // each block: 4 waves x 64 rows
    qnet_kernel<<<blocks, 256, 0, stream>>>(x, pre_w, pre_b, qp, post_w, post_b, out, B);
}

// Round 3
// 94.345 us; speedup vs baseline: 1.0523x; 1.0523x over previous
//
#include <hip/hip_runtime.h>
#include <math.h>

#define DIN 512
#define NQ 4
#define DEPTH 6
#define RB 8   // rows per prefetch batch

typedef float fx4 __attribute__((ext_vector_type(4)));

__device__ __forceinline__ float shflx(float v, int mask) {
    return __shfl_xor(v, mask, 64);
}

__device__ __forceinline__ float rfl(float x) {
    return __uint_as_float(__builtin_amdgcn_readfirstlane(__float_as_uint(x)));
}

__global__ __launch_bounds__(256, 4) void qnet_kernel(
    const float* __restrict__ x,       // (B, 512)
    const float* __restrict__ pre_w,   // (4, 512)
    const float* __restrict__ pre_b,   // (4,)
    const float* __restrict__ qp,      // (24,)
    const float* __restrict__ post_w,  // (2, 4)
    const float* __restrict__ post_b,  // (2,)
    float* __restrict__ out,           // (B, 2)
    int B)
{
    __shared__ float qbuf[4][64][5];   // [wave][row-in-batch][qubit], +1 pad

    const int tid  = threadIdx.x;
    const int lane = tid & 63;
    const int wv   = tid >> 6;
    const long long wave_global = ((long long)blockIdx.x * (long long)blockDim.x + tid) >> 6;
    const long long row_base = wave_global * 64;

    const int c0 = lane * 4;          // cols [0,256) as lane*4
    const int c1 = 256 + lane * 4;    // cols [256,512)

    // pre_w fragment: 8 floats per qubit per lane, loaded once (L1/L2-hot, tiny)
    fx4 w0[NQ], w1[NQ];
#pragma unroll
    for (int q = 0; q < NQ; ++q) {
        w0[q] = *reinterpret_cast<const fx4*>(pre_w + q * DIN + c0);
        w1[q] = *reinterpret_cast<const fx4*>(pre_w + q * DIN + c1);
    }

    const bool odd  = (lane & 1) != 0;
    const bool bit2 = (lane & 2) != 0;
    const int  quad = lane >> 2;
    const int  qq   = lane & 3;

    const long long maxrow = (long long)B - 1;

    // ---- Phase 1: 64 rows per wave, in batches of RB=8 prefetched rows ----
    // 16 back-to-back global_load_dwordx4 per batch (16 KB/wave in flight),
    // then 8 independent reduction chains drain them vmcnt-staggered.
#pragma unroll 1
    for (int jb = 0; jb < 64; jb += RB) {
        fx4 A[RB], Bv[RB];
#pragma unroll
        for (int u = 0; u < RB; ++u) {
            long long row = row_base + jb + u;
            if (row > maxrow) row = maxrow;       // wave-uniform clamp (SALU)
            const float* xr = x + row * DIN;
            A[u]  = __builtin_nontemporal_load(reinterpret_cast<const fx4*>(xr + c0));
            Bv[u] = __builtin_nontemporal_load(reinterpret_cast<const fx4*>(xr + c1));
        }
#pragma unroll
        for (int u = 0; u < RB; ++u) {
            const int j = jb + u;
            const fx4 a = A[u];
            const fx4 b = Bv[u];

            float p[NQ];
#pragma unroll
            for (int q = 0; q < NQ; ++q) {
                float s = a.x * w0[q].x;
                s = fmaf(a.y, w0[q].y, s);
                s = fmaf(a.z, w0[q].z, s);
                s = fmaf(a.w, w0[q].w, s);
                s = fmaf(b.x, w1[q].x, s);
                s = fmaf(b.y, w1[q].y, s);
                s = fmaf(b.z, w1[q].z, s);
                s = fmaf(b.w, w1[q].w, s);
                p[q] = s;
            }

            // merged reduction: fold 4 q-values into lane%4 slots during xor-1/xor-2
            float s0 = p[0] + shflx(p[0], 1);
            float s1 = p[1] + shflx(p[1], 1);
            float s2 = p[2] + shflx(p[2], 1);
            float s3 = p[3] + shflx(p[3], 1);
            float a01 = odd  ? s1 : s0;
            float a23 = odd  ? s3 : s2;
            float u01 = a01 + shflx(a01, 2);
            float u23 = a23 + shflx(a23, 2);
            float c = bit2 ? u23 : u01;   // lane l holds quad-partial of dot[l&3]
            c += shflx(c, 4);
            c += shflx(c, 8);
            c += shflx(c, 16);
            c += shflx(c, 32);            // full sum of dot[l&3] on every lane

            if (quad == (j & 15)) qbuf[wv][j][qq] = c;   // 4 lanes deposit row j's dots
        }
    }

    __syncthreads();   // wave-local dependency really, but cheap & safe

    // ---- Phase 2: each lane simulates the circuit for its own row ----
    float d0 = qbuf[wv][lane][0] + pre_b[0];
    float d1 = qbuf[wv][lane][1] + pre_b[1];
    float d2 = qbuf[wv][lane][2] + pre_b[2];
    float d3 = qbuf[wv][lane][3] + pre_b[3];

    const float QPI = 0.7853981633974483f;   // pi/4: half of q_in = tanh*pi/2
    float h0 = QPI * tanhf(d0);
    float h1 = QPI * tanhf(d1);
    float h2 = QPI * tanhf(d2);
    float h3 = QPI * tanhf(d3);

    float cc[NQ], ss[NQ];
    __sincosf(h0, &ss[0], &cc[0]);
    __sincosf(h1, &ss[1], &cc[1]);
    __sincosf(h2, &ss[2], &cc[2]);
    __sincosf(h3, &ss[3], &cc[3]);

    // per-wire 2-vector after H then RY(theta_w): ((c-s)/sqrt2, (c+s)/sqrt2)
    const float RS2 = 0.7071067811865476f;
    float e[NQ][2];
#pragma unroll
    for (int w = 0; w < NQ; ++w) {
        e[w][0] = (cc[w] - ss[w]) * RS2;
        e[w][1] = (cc[w] + ss[w]) * RS2;
    }

    // idx = i0*8 + i1*4 + i2*2 + i3   (wire w <-> bit 3-w)
    float st[16];
#pragma unroll
    for (int hi = 0; hi < 4; ++hi) {
        float m01 = e[0][hi >> 1] * e[1][hi & 1];
#pragma unroll
        for (int lo = 0; lo < 4; ++lo) {
            st[hi * 4 + lo] = m01 * (e[2][lo >> 1] * e[3][lo & 1]);
        }
    }

#pragma unroll
    for (int k = 0; k < DEPTH; ++k) {
        // CNOT(0,1): idx bit3=1 -> flip bit2 : swap 8..11 <-> 12..15
#pragma unroll
        for (int m = 0; m < 4; ++m) { float t = st[8 + m]; st[8 + m] = st[12 + m]; st[12 + m] = t; }
        // CNOT(2,3): idx bit1=1 -> flip bit0 : swap (2,3),(6,7),(10,11),(14,15)
#pragma unroll
        for (int m = 0; m < 4; ++m) { int i = 4 * m + 2; float t = st[i]; st[i] = st[i + 1]; st[i + 1] = t; }
        // CNOT(1,2): idx bit2=1 -> flip bit1 : swap (4,6),(5,7),(12,14),(13,15)
        {
            float t;
            t = st[4];  st[4]  = st[6];  st[6]  = t;
            t = st[5];  st[5]  = st[7];  st[7]  = t;
            t = st[12]; st[12] = st[14]; st[14] = t;
            t = st[13]; st[13] = st[15]; st[15] = t;
        }
        // RY(qw[k][w]) on each wire; angles wave-uniform -> SGPR via readfirstlane
#pragma unroll
        for (int w = 0; w < NQ; ++w) {
            float ang = 0.5f * qp[k * NQ + w];
            float sk, ck;
            __sincosf(ang, &sk, &ck);
            ck = rfl(ck);
            sk = rfl(sk);
            const int mask = 8 >> w;
#pragma unroll
            for (int i = 0; i < 16; ++i) {
                if ((i & mask) == 0) {
                    float lo = st[i], hi = st[i + mask];
                    st[i]        = fmaf(ck, lo, -(sk * hi));
                    st[i + mask] = fmaf(sk, lo, ck * hi);
                }
            }
        }
    }

    // Z expectations: z_w = sum_i sign(bit(3-w) of i) * st[i]^2
    float z0 = 0.f, z1 = 0.f, z2 = 0.f, z3 = 0.f;
#pragma unroll
    for (int i = 0; i < 16; ++i) {
        float pr = st[i] * st[i];
        z0 += (i & 8) ? -pr : pr;
        z1 += (i & 4) ? -pr : pr;
        z2 += (i & 2) ? -pr : pr;
        z3 += (i & 1) ? -pr : pr;
    }

    float o0 = fmaf(z0, post_w[0], fmaf(z1, post_w[1], fmaf(z2, post_w[2], fmaf(z3, post_w[3], post_b[0]))));
    float o1 = fmaf(z0, post_w[4], fmaf(z1, post_w[5], fmaf(z2, post_w[6], fmaf(z3, post_w[7], post_b[1]))));

    long long row = row_base + lane;
    if (row < (long long)B) {
        float2 o; o.x = o0; o.y = o1;
        *reinterpret_cast<float2*>(out + row * 2) = o;
    }
}

extern "C" void kernel_launch(void* const* d_in, const int* in_sizes, int n_in,
                              void* d_out, int out_size, void* d_ws, size_t ws_size,
                              hipStream_t stream) {
    const float* x      = (const float*)d_in[0];
    const float* pre_w  = (const float*)d_in[1];
    const float* pre_b  = (const float*)d_in[2];
    const float* qp     = (const float*)d_in[3];
    const float* post_w = (const float*)d_in[4];
    const float* post_b = (const float*)d_in[5];
    float* out = (float*)d_out;

    const int B = in_sizes[0] / DIN;
    if (B <= 0) return;
    const int blocks = (B + 255) / 256;   // each block: 4 waves x 64 rows
    qnet_kernel<<<blocks, 256, 0, stream>>>(x, pre_w, pre_b, qp, post_w, post_b, out, B);
}